// Round 15
// baseline (708.678 us; speedup 1.0000x reference)
//
#include <hip/hip_runtime.h>

#define CH 128
#define MM 64
#define BB 128
#define NN 4096
#define QN 1024                // n-rows per quarter-block
#define KSTEP 32
#define NSTEP (QN / KSTEP)     // 32
#define UBUF (KSTEP * MM)      // 2048 floats
#define HBUF (KSTEP * CH)      // 4096 floats
#define BUF  (UBUF + HBUF)     // 6144 floats = 24 KB
#define MMCH (MM * CH)         // 8192

typedef __bf16 bf16x8 __attribute__((ext_vector_type(8)));
typedef float  f32x4  __attribute__((ext_vector_type(4)));

#define AS1(p) ((const __attribute__((address_space(1))) void*)(p))
#define AS3(p) ((__attribute__((address_space(3))) void*)(p))

__device__ __forceinline__ void gl_lds16(const float* g, float* l) {
    __builtin_amdgcn_global_load_lds(AS1(g), AS3(l), 16, 0, 0);
}

// group-of-4 blocks barrier: device-scope release -> count -> spin -> acquire
__device__ __forceinline__ void group_sync(int* c, int tid) {
    __threadfence();
    __syncthreads();
    if (tid == 0) {
        atomicAdd(c, 1);
        while (atomicAdd(c, 0) < 4) __builtin_amdgcn_s_sleep(2);
    }
    __syncthreads();
    __threadfence();
}

// ---------------------------------------------------------------------------
// Fused kernel: grid = 512 blocks (group of 4 per b; q = n-quarter), 512 thr =
// 8 waves, exactly 2 blocks/CU (72 KB LDS, <=128 VGPR) -> all co-resident.
// Phase 1 (R13 k1): partial[b][q] = U[b,nq]^T h[b,nq] via MFMA, async-LDS
//   staging (3 buf, depth-2, vmcnt 6/3/0). Wave wv: m-half wv>>2, c-qtr wv&3.
// Phase 2 (k2): group sync; block mixes modes [16q,16q+16): sum partials ->
//   LDS, W row-coalesced mix, pack bf16 MFMA-B-fragments to ohf[b].
// Phase 3 (k3): group sync; block computes out rows [q*1024,+1024) (same rows
//   it read in phase 1 -> cache-warm U), 8 iters x 128 rows, MFMA.
// Frag maps HW-validated R7/R8/R10.
// ---------------------------------------------------------------------------
__global__ __launch_bounds__(512, 2) void fused_gsc(const float* __restrict__ U,
                                                    const float* __restrict__ h,
                                                    const float* __restrict__ W,
                                                    float* __restrict__ part,
                                                    __bf16* __restrict__ ohf,
                                                    int* __restrict__ cnt,
                                                    float* __restrict__ out) {
    __shared__ float lds[3 * BUF];     // 72 KB

    const int tid  = threadIdx.x;
    const int lane = tid & 63;
    const int wv   = tid >> 6;         // 0..7
    const int b    = blockIdx.x >> 2;
    const int q    = blockIdx.x & 3;
    const int k0   = q * QN;

    const int l15  = lane & 15;
    const int g    = lane >> 4;
    const int lk   = g * 8;
    const int half = wv >> 2;          // phase-1 m-half
    const int cq   = wv & 3;           // phase-1 c-quarter

    // ======================= phase 1 =======================
    const float* Ub = U + ((size_t)b * NN + k0) * MM;
    const float* hb = h + ((size_t)b * NN + k0) * CH;

    auto stage = [&](int s, int t) {   // 3 gl_lds16 per thread (24 KB/block)
        float* dst = &lds[s * BUF];
        const float* us = Ub + (size_t)t * KSTEP * MM;
        const float* hs = hb + (size_t)t * KSTEP * CH;
        gl_lds16(us + tid * 4,        dst + tid * 4);
        gl_lds16(hs + tid * 4,        dst + UBUF + tid * 4);
        gl_lds16(hs + 2048 + tid * 4, dst + UBUF + 2048 + tid * 4);
    };

    f32x4 acc1[2][2];
    #pragma unroll
    for (int p = 0; p < 2; ++p)
        #pragma unroll
        for (int ci = 0; ci < 2; ++ci)
            acc1[p][ci] = (f32x4){0.f, 0.f, 0.f, 0.f};

    auto compute1 = [&](int s) {
        const float* P  = &lds[s * BUF];
        const float* Pa = P + lk * 64 + half * 32 + 2 * l15;
        const float* Pb = P + UBUF + lk * 128 + cq * 32 + 2 * l15;
        bf16x8 af[2], bfr[2];
        #pragma unroll
        for (int j = 0; j < 8; ++j) {
            float2 av = *(const float2*)(Pa + j * 64);
            float2 bv = *(const float2*)(Pb + j * 128);
            af[0][j]  = (__bf16)av.x;   // m = half*32 + 2r
            af[1][j]  = (__bf16)av.y;   // m = half*32 + 2r+1
            bfr[0][j] = (__bf16)bv.x;   // c = cq*32 + 2c'
            bfr[1][j] = (__bf16)bv.y;   // c = cq*32 + 2c'+1
        }
        #pragma unroll
        for (int p = 0; p < 2; ++p)
            #pragma unroll
            for (int ci = 0; ci < 2; ++ci)
                acc1[p][ci] = __builtin_amdgcn_mfma_f32_16x16x32_bf16(
                    af[p], bfr[ci], acc1[p][ci], 0, 0, 0);
    };

    stage(0, 0);
    stage(1, 1);
    #pragma unroll 1
    for (int t = 0; t < NSTEP; ++t) {
        if (t + 2 < NSTEP) {
            stage((t + 2) % 3, t + 2);
            asm volatile("s_waitcnt vmcnt(6)" ::: "memory");
        } else if (t + 1 < NSTEP) {
            asm volatile("s_waitcnt vmcnt(3)" ::: "memory");
        } else {
            asm volatile("s_waitcnt vmcnt(0)" ::: "memory");
        }
        __builtin_amdgcn_s_barrier();
        __builtin_amdgcn_sched_barrier(0);
        compute1(t % 3);
        __builtin_amdgcn_s_barrier();
    }

    {   // store partial (b,q): m = half*32 + 2*(g*4+r) + par, c = cq*32+2*l15+ci
        float* pdst = part + (size_t)(b * 4 + q) * MMCH + cq * 32 + 2 * l15;
        #pragma unroll
        for (int p = 0; p < 2; ++p)
            #pragma unroll
            for (int r = 0; r < 4; ++r) {
                const int m = half * 32 + 2 * (g * 4 + r) + p;
                *(float2*)(pdst + (size_t)m * CH) =
                    make_float2(acc1[p][0][r], acc1[p][1][r]);
            }
    }

    group_sync(&cnt[b * 2 + 0], tid);

    // ======================= phase 2 =======================
    {   // sum 4 partials for m-slice [16q,16q+16) into lds[0..2047]
        const int lm = tid >> 5;             // 0..15
        const int c4 = (tid & 31) * 4;
        const float* p0 = part + (size_t)(b * 4) * MMCH
                               + (size_t)(q * 16 + lm) * CH + c4;
        float4 s0 = *(const float4*)(p0);
        float4 s1 = *(const float4*)(p0 + MMCH);
        float4 s2 = *(const float4*)(p0 + 2 * MMCH);
        float4 s3 = *(const float4*)(p0 + 3 * MMCH);
        float4 sm = make_float4(s0.x + s1.x + s2.x + s3.x,
                                s0.y + s1.y + s2.y + s3.y,
                                s0.z + s1.z + s2.z + s3.z,
                                s0.w + s1.w + s2.w + s3.w);
        *(float4*)&lds[lm * CH + c4] = sm;
    }
    __syncthreads();

    #pragma unroll
    for (int s = 0; s < 2; ++s) {          // wave handles 2 modes
        const int lm = wv * 2 + s;
        const int m  = q * 16 + lm;
        const float* Wm = W + (size_t)m * CH * CH;
        float a0 = 0.f, a1 = 0.f;
        #pragma unroll 4
        for (int c = 0; c < CH; ++c) {
            const float hhv = lds[lm * CH + c];
            a0 += hhv * Wm[c * CH + lane];        // o = lane
            a1 += hhv * Wm[c * CH + 64 + lane];   // o = 64+lane
        }
        // pack to MFMA-B-fragment order (k2 formula, HW-validated R7)
        const int mt  = m >> 5;
        const int lhi = (m & 31) >> 3;
        const int j   = m & 7;
        const int fl  = lhi * 16 + l15;
        ohf[(size_t)b * 8192 + ((size_t)(mt * 8 + g)     * 64 + fl) * 8 + j] = (__bf16)a0;
        ohf[(size_t)b * 8192 + ((size_t)(mt * 8 + 4 + g) * 64 + fl) * 8 + j] = (__bf16)a1;
    }

    group_sync(&cnt[b * 2 + 1], tid);

    // ======================= phase 3 =======================
    const __bf16* ohfb = ohf + (size_t)b * 8192;
    #pragma unroll 1
    for (int it = 0; it < 8; ++it) {
        const int n0 = q * QN + it * 128 + wv * 16;
        const float* arow = U + ((size_t)b * NN + n0 + l15) * MM + (g << 3);
        bf16x8 af2[2];
        #pragma unroll
        for (int mt = 0; mt < 2; ++mt) {
            float4 a0 = *(const float4*)(arow + mt * 32);
            float4 a1 = *(const float4*)(arow + mt * 32 + 4);
            af2[mt][0] = (__bf16)a0.x; af2[mt][1] = (__bf16)a0.y;
            af2[mt][2] = (__bf16)a0.z; af2[mt][3] = (__bf16)a0.w;
            af2[mt][4] = (__bf16)a1.x; af2[mt][5] = (__bf16)a1.y;
            af2[mt][6] = (__bf16)a1.z; af2[mt][7] = (__bf16)a1.w;
        }
        f32x4 acc3[8];
        #pragma unroll
        for (int ot = 0; ot < 8; ++ot) acc3[ot] = (f32x4){0.f, 0.f, 0.f, 0.f};
        #pragma unroll
        for (int ot = 0; ot < 8; ++ot) {
            bf16x8 b0 = *(const bf16x8*)(ohfb + ((size_t)(0 * 8 + ot) * 64 + lane) * 8);
            bf16x8 b1 = *(const bf16x8*)(ohfb + ((size_t)(1 * 8 + ot) * 64 + lane) * 8);
            acc3[ot] = __builtin_amdgcn_mfma_f32_16x16x32_bf16(af2[0], b0, acc3[ot], 0, 0, 0);
            acc3[ot] = __builtin_amdgcn_mfma_f32_16x16x32_bf16(af2[1], b1, acc3[ot], 0, 0, 0);
        }
        float* dst = out + ((size_t)b * NN + n0 + g * 4) * CH + l15;
        #pragma unroll
        for (int ot = 0; ot < 8; ++ot)
            #pragma unroll
            for (int r = 0; r < 4; ++r)
                dst[(size_t)r * CH + ot * 16] = acc3[ot][r];
    }
}

// ---------------------------------------------------------------------------
extern "C" void kernel_launch(void* const* d_in, const int* in_sizes, int n_in,
                              void* d_out, int out_size, void* d_ws, size_t ws_size,
                              hipStream_t stream) {
    const float* h = (const float*)d_in[0];   // [B*N, C]
    const float* U = (const float*)d_in[1];   // [B, N, M]
    const float* W = (const float*)d_in[2];   // [M, C, C]
    float* out = (float*)d_out;

    float*  part = (float*)d_ws;                               // [B*4, M, C] 16 MB
    __bf16* ohf  = (__bf16*)(part + (size_t)BB * 4 * MMCH);    // [B, 8192]    2 MB
    int*    cnt  = (int*)(ohf + (size_t)BB * 8192);            // [B, 2]

    hipMemsetAsync(cnt, 0, BB * 2 * sizeof(int), stream);
    fused_gsc<<<BB * 4, 512, 0, stream>>>(U, h, W, part, ohf, cnt, out);
}

// Round 16
// 231.775 us; speedup vs baseline: 3.0576x; 3.0576x over previous
//
#include <hip/hip_runtime.h>

#define CH 128
#define MM 64
#define BB 128
#define NN 4096
#define KSPLIT 8
#define KCHUNK (NN / KSPLIT)   // 512
#define NSTEP (KCHUNK / 32)    // 16
#define MMCH (MM * CH)

typedef __bf16 bf16x8 __attribute__((ext_vector_type(8)));
typedef float  f32x4  __attribute__((ext_vector_type(4)));

// ---------------------------------------------------------------------------
// Kernel 1 (TLP-first MFMA): partial[b][ks][m][c] = sum_n U[b][n][m]*h[b][n][c]
// grid: BB*KSPLIT = 1024 blocks x 512 thr = 8 waves; wave wv: m-half wv>>2,
// c-quarter wv&3. NO LDS, NO barriers, single-buffered float2 loads ->
// ~75 VGPR, __launch_bounds__(512,6): 6 waves/SIMD = 24 waves/CU (3x R13).
// TLP hides HBM latency (k3's model — 44 VGPR/32 waves/5.4 TB/s).
// 8 waves of one (b,ks) co-resident on one CU -> U(x4)/h(x2) overlap dedups
// in L1; HBM traffic stays ~402 MB.
// Remap (HW-validated R10): af[0/1] <- m = mh*32 + {2r, 2r+1};
// bf[0/1] <- c = cq*32 + {2c', 2c'+1}; k = (l>>4)*8 + j on both -> invariant.
// ---------------------------------------------------------------------------
__global__ __launch_bounds__(512, 6) void k1_uth(const float* __restrict__ U,
                                                 const float* __restrict__ h,
                                                 float* __restrict__ hhp) {
    const int tid  = threadIdx.x;
    const int lane = tid & 63;
    const int wv   = tid >> 6;          // 0..7
    const int mh   = wv >> 2;           // 0,1  -> m-half
    const int cq   = wv & 3;            // 0..3 -> c-quarter
    const int b    = blockIdx.x >> 3;   // KSPLIT = 8
    const int ks   = blockIdx.x & 7;
    const int k0   = ks * KCHUNK;

    const int l15 = lane & 15;
    const int g   = lane >> 4;
    const int lk  = g * 8;              // k-offset within 32

    const float* Ua = U + ((size_t)b * NN + k0 + lk) * MM + mh * 32 + 2 * l15;
    const float* ha = h + ((size_t)b * NN + k0 + lk) * CH + cq * 32 + 2 * l15;

    f32x4 acc[2][2];
    #pragma unroll
    for (int p = 0; p < 2; ++p)
        #pragma unroll
        for (int ci = 0; ci < 2; ++ci)
            acc[p][ci] = (f32x4){0.f, 0.f, 0.f, 0.f};

    #pragma unroll 1
    for (int t = 0; t < NSTEP; ++t) {
        const float* ua = Ua + (size_t)t * 32 * MM;
        const float* hb = ha + (size_t)t * 32 * CH;
        float2 ar[8], br[8];
        #pragma unroll
        for (int j = 0; j < 8; ++j) {
            ar[j] = *(const float2*)(ua + j * MM);
            br[j] = *(const float2*)(hb + j * CH);
        }
        bf16x8 af[2], bfr[2];
        #pragma unroll
        for (int j = 0; j < 8; ++j) {
            af[0][j]  = (__bf16)ar[j].x;   // m = mh*32 + 2r
            af[1][j]  = (__bf16)ar[j].y;   // m = mh*32 + 2r+1
            bfr[0][j] = (__bf16)br[j].x;   // c = cq*32 + 2c'
            bfr[1][j] = (__bf16)br[j].y;   // c = cq*32 + 2c'+1
        }
        #pragma unroll
        for (int p = 0; p < 2; ++p)
            #pragma unroll
            for (int ci = 0; ci < 2; ++ci)
                acc[p][ci] = __builtin_amdgcn_mfma_f32_16x16x32_bf16(
                    af[p], bfr[ci], acc[p][ci], 0, 0, 0);
    }

    // store: D[row=g*4+r][col=l15]; m = mh*32 + 2*(g*4+r) + p;
    // c = cq*32 + 2*l15 + ci -> ci pair merges into one float2.
    float* dst = hhp + (size_t)(b * KSPLIT + ks) * MMCH + cq * 32 + 2 * l15;
    #pragma unroll
    for (int p = 0; p < 2; ++p)
        #pragma unroll
        for (int r = 0; r < 4; ++r) {
            const int m = mh * 32 + 2 * (g * 4 + r) + p;
            *(float2*)(dst + (size_t)m * CH) =
                make_float2(acc[p][0][r], acc[p][1][r]);
        }
}

// ---------------------------------------------------------------------------
// Kernel 2 (R8's KSPLIT=8 version, unchanged): oh[b][m][o] =
// sum_c (sum_ks partial) * W[m][c][o], stored bf16 in MFMA B-fragment order.
// grid: (MM, BB/16), 256 threads.
// ---------------------------------------------------------------------------
__global__ __launch_bounds__(256) void k2_mix(const float* __restrict__ hhp,
                                              const float* __restrict__ W,
                                              __bf16* __restrict__ ohf) {
    __shared__ float hs[16][CH];
    const int tid  = threadIdx.x;
    const int o    = tid & 127;
    const int half = tid >> 7;
    const int m    = blockIdx.x;
    const int b0   = blockIdx.y * 16;

    #pragma unroll
    for (int i = 0; i < 8; ++i) {
        const int b = b0 + half * 8 + i;
        const float* src = hhp + ((size_t)(b * KSPLIT) * MM + m) * CH + o;
        float s = 0.f;
        #pragma unroll
        for (int ksi = 0; ksi < KSPLIT; ++ksi)
            s += src[(size_t)ksi * MMCH];
        hs[half * 8 + i][o] = s;
    }
    __syncthreads();

    float acc[8];
    #pragma unroll
    for (int i = 0; i < 8; ++i) acc[i] = 0.f;

    const float* Wm = W + (size_t)m * CH * CH;
    for (int c = 0; c < CH; ++c) {
        const float w = Wm[c * CH + o];
        #pragma unroll
        for (int i = 0; i < 8; ++i) acc[i] += hs[half * 8 + i][c] * w;
    }

    const int mt      = m >> 5;
    const int m5      = m & 31;
    const int lane_hi = m5 >> 3;
    const int j       = m5 & 7;
    const int ot      = o >> 4;
    const int lane    = lane_hi * 16 + (o & 15);
    const size_t eidx = ((size_t)(mt * 8 + ot) * 64 + lane) * 8 + j;

    #pragma unroll
    for (int i = 0; i < 8; ++i) {
        const int b = b0 + half * 8 + i;
        ohf[(size_t)b * 8192 + eidx] = (__bf16)acc[i];
    }
}

// ---------------------------------------------------------------------------
// Kernel 3 (unchanged from R8/R10/R13): out[b][n][o] = sum_m U[b][n][m]*oh[b][m][o].
// grid: (NN/64, BB), 256 threads = 4 waves, wave = 16 n-rows.
// ---------------------------------------------------------------------------
__global__ __launch_bounds__(256) void k3_back(const float* __restrict__ U,
                                               const __bf16* __restrict__ ohf,
                                               float* __restrict__ out) {
    const int tid  = threadIdx.x;
    const int lane = tid & 63;
    const int wv   = tid >> 6;
    const int n0   = blockIdx.x * 64;
    const int b    = blockIdx.y;

    const bf16x8* ohfb = (const bf16x8*)(ohf + (size_t)b * 8192);
    bf16x8 bf[2][8];
    #pragma unroll
    for (int mt = 0; mt < 2; ++mt)
        #pragma unroll
        for (int ot = 0; ot < 8; ++ot)
            bf[mt][ot] = ohfb[(mt * 8 + ot) * 64 + lane];

    const float* arow = U + ((size_t)b * NN + n0 + wv * 16 + (lane & 15)) * MM
                          + ((lane >> 4) << 3);
    bf16x8 af[2];
    #pragma unroll
    for (int mt = 0; mt < 2; ++mt) {
        float4 a0 = *(const float4*)(arow + mt * 32);
        float4 a1 = *(const float4*)(arow + mt * 32 + 4);
        af[mt][0] = (__bf16)a0.x; af[mt][1] = (__bf16)a0.y;
        af[mt][2] = (__bf16)a0.z; af[mt][3] = (__bf16)a0.w;
        af[mt][4] = (__bf16)a1.x; af[mt][5] = (__bf16)a1.y;
        af[mt][6] = (__bf16)a1.z; af[mt][7] = (__bf16)a1.w;
    }

    f32x4 acc[8];
    #pragma unroll
    for (int ot = 0; ot < 8; ++ot) acc[ot] = (f32x4){0.f, 0.f, 0.f, 0.f};

    #pragma unroll
    for (int ot = 0; ot < 8; ++ot) {
        acc[ot] = __builtin_amdgcn_mfma_f32_16x16x32_bf16(af[0], bf[0][ot], acc[ot], 0, 0, 0);
        acc[ot] = __builtin_amdgcn_mfma_f32_16x16x32_bf16(af[1], bf[1][ot], acc[ot], 0, 0, 0);
    }

    float* dst = out + ((size_t)b * NN + n0 + wv * 16 + (lane >> 4) * 4) * CH + (lane & 15);
    #pragma unroll
    for (int ot = 0; ot < 8; ++ot)
        #pragma unroll
        for (int r = 0; r < 4; ++r)
            dst[(size_t)r * CH + ot * 16] = acc[ot][r];
}

// ---------------------------------------------------------------------------
extern "C" void kernel_launch(void* const* d_in, const int* in_sizes, int n_in,
                              void* d_out, int out_size, void* d_ws, size_t ws_size,
                              hipStream_t stream) {
    const float* h = (const float*)d_in[0];   // [B*N, C]
    const float* U = (const float*)d_in[1];   // [B, N, M]
    const float* W = (const float*)d_in[2];   // [M, C, C]
    float* out = (float*)d_out;

    float*  hhp = (float*)d_out;              // [B*KSPLIT, M, C] partials (32 MB)
    __bf16* ohf = (__bf16*)d_ws;              // [B, 8192] bf16 B-fragments (2 MB)

    k1_uth<<<BB * KSPLIT, 512, 0, stream>>>(U, h, hhp);
    k2_mix<<<dim3(MM, BB / 16), 256, 0, stream>>>(hhp, W, ohf);
    k3_back<<<dim3(NN / 64, BB), 256, 0, stream>>>(U, ohf, out);
}